// Round 6
// baseline (333.788 us; speedup 1.0000x reference)
//
#include <hip/hip_runtime.h>
#include <stdint.h>

#define NG 4
#define NK 160
#define GD 128
#define ED 512
#define BB 16
#define TT 4096
static constexpr size_t ZSZ = (size_t)BB * ED * TT;           // 33554432

// d_out FLOAT32: [0,ZSZ) z_q | [ZSZ] loss | codes after.
// ws (floats): [0,1024) bsum | [1024,1664) sc | [2048, 2048+81920) ct[g][d][k]

// ---------------- prep: transpose codebook to [g][d][k] + codeword norms ---
__global__ void prep_kernel(const float* __restrict__ cb, float* __restrict__ sc,
                            float* __restrict__ ct) {
  int i = blockIdx.x * 256 + threadIdx.x;                 // 81920 total
  int g = i / (GD * NK), r = i % (GD * NK), d = r / NK, k = r % NK;
  ct[i] = cb[((size_t)g * NK + k) * GD + d];
  if (i < NG * NK) {
    const float* c = cb + (size_t)i * GD;
    float s = 0.f;
    for (int dd = 0; dd < GD; ++dd) s = fmaf(c[dd], c[dd], s);
    sc[i] = s;
  }
}

// ---------------- phase compute: 4 tokens x TC codes register tile ---------
template <int TC>
__device__ __forceinline__ void phase_compute(const float* xs, const float* cts,
                                              const float* scp, int l, int co, int kc,
                                              const float sx[4], float best[4],
                                              int bik[4]) {
  float acc[4][TC];
#pragma unroll
  for (int i = 0; i < 4; ++i)
#pragma unroll
    for (int c = 0; c < TC; ++c) acc[i][c] = 0.f;
#pragma unroll 2
  for (int d = 0; d < GD; ++d) {                          // ascending d: same
    const float4 xv = *(const float4*)&xs[d * 256 + l * 4];  // chain as r3-r5
#pragma unroll
    for (int c4 = 0; c4 < TC / 4; ++c4) {
      const float4 cf = *(const float4*)&cts[d * (4 * TC) + co + c4 * 4];
      const float cv[4] = {cf.x, cf.y, cf.z, cf.w};
#pragma unroll
      for (int u = 0; u < 4; ++u) {
        const int c = c4 * 4 + u;
        acc[0][c] = fmaf(xv.x, cv[u], acc[0][c]);
        acc[1][c] = fmaf(xv.y, cv[u], acc[1][c]);
        acc[2][c] = fmaf(xv.z, cv[u], acc[2][c]);
        acc[3][c] = fmaf(xv.w, cv[u], acc[3][c]);
      }
    }
  }
#pragma unroll
  for (int c = 0; c < TC; ++c) {
    const float scv = scp[kc + c];
#pragma unroll
    for (int i = 0; i < 4; ++i) {
      const float dk = (sx[i] + scv) - 2.0f * acc[i][c];  // ref formula order
      if (dk < best[i]) { best[i] = dk; bik[i] = kc + c; }
    }
  }
}

// ---------------- main: 256 tokens/block, 4 waves split 160 codes ----------
__global__ __launch_bounds__(256, 1) void vq_kernel(const float* __restrict__ xin,
                                                    const float* __restrict__ cb,
                                                    const float* __restrict__ sc,
                                                    const float* __restrict__ ct,
                                                    float* __restrict__ out,
                                                    float* __restrict__ bsum) {
  __shared__ __align__(16) float xs[GD * 256];            // 128 KB, [d][tok]
  __shared__ __align__(16) float cts[64 * GD];            // 32 KB, [d][kp]

  const int tid = threadIdx.x;
  const int w = tid >> 6;                                 // wave 0..3
  const int l = tid & 63;
  const int g = (int)(blockIdx.x >> 8);
  const int widx = (int)(blockIdx.x & 255);
  const int b = widx >> 4;
  const int t0 = (widx & 15) << 8;                        // 256-token window

  const float* xbase = xin + ((size_t)(b * ED + g * GD)) * TT + t0;
  const float* ctg = ct + (size_t)g * GD * NK;
  const float* scg = sc + g * NK;

  // stage x: wave w stages d-rows [w*32, w*32+32)
#pragma unroll 4
  for (int i = 0; i < 32; ++i) {
    int d = w * 32 + i;
    float4 v = *(const float4*)(xbase + (size_t)d * TT + l * 4);
    *(float4*)&xs[d * 256 + l * 4] = v;
  }
  // stage ct phase 0 (codes 0..63): 8192 floats/wave-quarter = 8 iters
#pragma unroll
  for (int i = 0; i < 8; ++i) {
    int q = w * 512 + i * 64 + l;                         // float4 index
    int f = q * 4, d = f >> 6, kp = f & 63;
    *(float4*)&cts[d * 64 + kp] = *(const float4*)(ctg + (size_t)d * NK + kp);
  }
  __syncthreads();

  // sx for this lane's 4 tokens (ascending d, same chain as r3-r5)
  float sx[4] = {0.f, 0.f, 0.f, 0.f};
  for (int d = 0; d < GD; ++d) {
    const float4 v = *(const float4*)&xs[d * 256 + l * 4];
    sx[0] = fmaf(v.x, v.x, sx[0]);
    sx[1] = fmaf(v.y, v.y, sx[1]);
    sx[2] = fmaf(v.z, v.z, sx[2]);
    sx[3] = fmaf(v.w, v.w, sx[3]);
  }

  float best[4] = {3.4e38f, 3.4e38f, 3.4e38f, 3.4e38f};
  int bik[4] = {0, 0, 0, 0};

  phase_compute<16>(xs, cts, scg, l, w * 16, w * 16, sx, best, bik);
  __syncthreads();
  // stage ct phase 1 (codes 64..127)
#pragma unroll
  for (int i = 0; i < 8; ++i) {
    int q = w * 512 + i * 64 + l;
    int f = q * 4, d = f >> 6, kp = f & 63;
    *(float4*)&cts[d * 64 + kp] = *(const float4*)(ctg + (size_t)d * NK + 64 + kp);
  }
  __syncthreads();
  phase_compute<16>(xs, cts, scg, l, w * 16, 64 + w * 16, sx, best, bik);
  __syncthreads();
  // stage ct phase 2 (codes 128..159): 4096 floats/wave-quarter = 4 iters
#pragma unroll
  for (int i = 0; i < 4; ++i) {
    int q = w * 256 + i * 64 + l;
    int f = q * 4, d = f >> 5, kp = f & 31;
    *(float4*)&cts[d * 32 + kp] = *(const float4*)(ctg + (size_t)d * NK + 128 + kp);
  }
  __syncthreads();
  phase_compute<8>(xs, cts, scg, l, w * 8, 128 + w * 8, sx, best, bik);

  // ---- cross-wave merge (reuse cts) ----
  __syncthreads();
  float* bestL = cts;                                     // [w*256 + tok]
  int* bikL = (int*)(cts + 1024);
  *(float4*)&bestL[w * 256 + l * 4] = make_float4(best[0], best[1], best[2], best[3]);
  *(int4*)&bikL[w * 256 + l * 4] = make_int4(bik[0], bik[1], bik[2], bik[3]);
  __syncthreads();

  float bf = bestL[tid];
  int kf = bikL[tid];
#pragma unroll
  for (int ww = 1; ww < 4; ++ww) {
    float bw = bestL[ww * 256 + tid];
    int kw = bikL[ww * 256 + tid];
    if (bw < bf || (bw == bf && kw < kf)) { bf = bw; kf = kw; }  // np first-index
  }

  // codes_out[b, g, t0+tid]
  out[ZSZ + 1 + ((size_t)(b * NG + g)) * TT + t0 + tid] = (float)kf;

  // gather codeword into xs[d][tok] (thread j = token j writes its column)
  const float4* cw = (const float4*)(cb + ((size_t)g * NK + kf) * GD);
#pragma unroll 4
  for (int d4 = 0; d4 < 32; ++d4) {
    float4 v = cw[d4];
    xs[(d4 * 4 + 0) * 256 + tid] = v.x;
    xs[(d4 * 4 + 1) * 256 + tid] = v.y;
    xs[(d4 * 4 + 2) * 256 + tid] = v.z;
    xs[(d4 * 4 + 3) * 256 + tid] = v.w;
  }
  __syncthreads();

  // z_q stores: float4 along t, 32 per thread
  float* zbase = out + ((size_t)(b * ED + g * GD)) * TT + t0;
#pragma unroll 4
  for (int i = 0; i < 32; ++i) {
    int q = i * 256 + tid;                                // float4 index
    int d = q >> 6, tt = (q & 63) * 4;
    *(float4*)(zbase + (size_t)d * TT + tt) = *(const float4*)&xs[d * 256 + tt];
  }

  // loss partial: deterministic wave reduce then fixed-order block sum
  float s = bf;
#pragma unroll
  for (int off = 32; off > 0; off >>= 1) s += __shfl_down(s, off, 64);
  if (l == 0) bestL[w] = s;                               // cts reads all done
  __syncthreads();
  if (tid == 0)
    bsum[blockIdx.x] = ((bestL[0] + bestL[1]) + bestL[2]) + bestL[3];
}

// ---------------- loss ----------------
__global__ __launch_bounds__(64) void loss_kernel(const float* __restrict__ bsum,
                                                  float* __restrict__ out) {
  float s = 0.f;
  for (int j = 0; j < 16; ++j) s += bsum[threadIdx.x + 64 * j];
#pragma unroll
  for (int off = 32; off > 0; off >>= 1) s += __shfl_down(s, off, 64);
  if (threadIdx.x == 0) out[ZSZ] = 1.25f * s / (float)ZSZ;
}

extern "C" void kernel_launch(void* const* d_in, const int* in_sizes, int n_in,
                              void* d_out, int out_size, void* d_ws, size_t ws_size,
                              hipStream_t stream) {
  const float* xin = (const float*)d_in[0];
  const float* cb  = (const float*)d_in[1];
  float* out  = (float*)d_out;
  float* bsum = (float*)d_ws;            // 1024
  float* sc   = (float*)d_ws + 1024;     // 640
  float* ct   = (float*)d_ws + 2048;     // 81920

  prep_kernel<<<320, 256, 0, stream>>>(cb, sc, ct);
  vq_kernel<<<1024, 256, 0, stream>>>(xin, cb, sc, ct, out, bsum);
  loss_kernel<<<1, 64, 0, stream>>>(bsum, out);
}